// Round 5
// baseline (1657.299 us; speedup 1.0000x reference)
//
#include <hip/hip_runtime.h>
#include <math.h>

#define LOG0f (-1.0e30f)
#define ACTIVE_TH (-1.0e29f)
#define PRUNE_TH (-9.0f)
#define VCAB 128
#define HSZ 4096
#define HMASK (HSZ - 1)
#define MAXN 2052
#define HEMPTY 0xFFFFFFFFu

// JAX-exact logaddexp: max + log1p(exp(-|a-b|)) in f32
__device__ __forceinline__ float lae(float a, float b) {
    float mx = fmaxf(a, b);
    float d = fabsf(a - b);
    return mx + log1pf(expf(-d));
}
// monotonic float->uint transform (order-preserving)
__device__ __forceinline__ unsigned mono(float f) {
    unsigned u = __float_as_uint(f);
    return (u & 0x80000000u) ? ~u : (u | 0x80000000u);
}
__device__ __forceinline__ float mono_inv(unsigned m) {
    unsigned u = (m & 0x80000000u) ? (m & 0x7FFFFFFFu) : ~m;
    return __uint_as_float(u);
}

// 64-lane max of (hi,lo) u64 keys on the VALU pipe; result broadcast to ALL lanes.
#define ROR_STEP(CTRL)                                                                  \
    do {                                                                                \
        unsigned h2 = (unsigned)__builtin_amdgcn_update_dpp(0, (int)hi, (CTRL), 0xf, 0xf, false); \
        unsigned l2 = (unsigned)__builtin_amdgcn_update_dpp(0, (int)lo, (CTRL), 0xf, 0xf, false); \
        bool g = (h2 > hi) || (h2 == hi && l2 > lo);                                    \
        hi = g ? h2 : hi;                                                               \
        lo = g ? l2 : lo;                                                               \
    } while (0)

__device__ __forceinline__ void wave_max64(unsigned &hi, unsigned &lo) {
    ROR_STEP(0x121);  // row_ror:1
    ROR_STEP(0x122);  // row_ror:2
    ROR_STEP(0x124);  // row_ror:4
    ROR_STEP(0x128);  // row_ror:8  -> every lane holds its 16-row max
    {
        unsigned ah = hi, ch = hi, al = lo, cl = lo;
        asm("v_permlane16_swap_b32 %0, %1" : "+v"(ah), "+v"(ch));
        asm("v_permlane16_swap_b32 %0, %1" : "+v"(al), "+v"(cl));
        bool g = (ch > ah) || (ch == ah && cl > al);
        hi = g ? ch : ah;
        lo = g ? cl : al;
    }
    {
        unsigned ah = hi, ch = hi, al = lo, cl = lo;
        asm("v_permlane32_swap_b32 %0, %1" : "+v"(ah), "+v"(ch));
        asm("v_permlane32_swap_b32 %0, %1" : "+v"(al), "+v"(cl));
        bool g = (ch > ah) || (ch == ah && cl > al);
        hi = g ? ch : ah;
        lo = g ? cl : al;
    }
}

__global__ __launch_bounds__(64)
void ctc_beam_kernel(const float* __restrict__ probs, const int* __restrict__ lengths,
                     const int* __restrict__ blank_p, int* __restrict__ out_seq,
                     int* __restrict__ out_len, int T) {
    __shared__ unsigned hsh[HSZ];        // dedup map (parent,label)->node: (hkey<<12)|id
    __shared__ unsigned nodeinfo[MAXN];  // (parent<<7)|label per node id
    __shared__ int sh_seq[256];
    __shared__ unsigned ls_a[8], ls_b[8];  // per-round winner state (compact rolled loop)

    const int lane = threadIdx.x;
    const int b = blockIdx.x;
    const int blank = blank_p[0];
    const int length = lengths[b];
    const float* __restrict__ P = probs + (size_t)b * T * VCAB;
    const float4* __restrict__ P4 = (const float4*)P;
    const int own = lane & 7;     // beam owned by this lane
    const int slice = lane >> 3;  // vocab slice [slice*16, +16)
    const int vbase = slice * 16;

    for (int i = lane; i < HSZ; i += 64) hsh[i] = HEMPTY;
    __syncthreads();

    // wave-uniform beam metadata
    unsigned node8[8], par8[8], len8[8], last8[8];
#pragma unroll
    for (int j = 0; j < 8; ++j) {
        node8[j] = 0; par8[j] = 0xFFFu; len8[j] = 0; last8[j] = (unsigned)blank;
    }
    // per-lane own-beam state
    float pb_own = (own == 0) ? 0.0f : LOG0f;  // root: blank prob = log(1)
    float pnb_own = LOG0f;
    int len_own = 0, last_own = blank;
    unsigned node_own = 0, par_own = 0xFFFu;

    // prefetch row 0: slice (float4 x4) + shuffle layout (labels lane, lane+64)
    float4 s0, s1, s2, s3;
    float prL, prH;
    {
        int base4 = (vbase >> 2);
        s0 = P4[base4]; s1 = P4[base4 + 1]; s2 = P4[base4 + 2]; s3 = P4[base4 + 3];
        prL = P[lane]; prH = P[64 + lane];
    }

#pragma clang loop unroll(disable)
    for (int t = 0; t < length; ++t) {
        // prefetch t+1
        float4 n0, n1, n2, n3;
        float nprL = 0.f, nprH = 0.f;
        n0 = n1 = n2 = n3 = make_float4(0.f, 0.f, 0.f, 0.f);
        if (t + 1 < length) {
            int base4 = (t + 1) * 32 + (vbase >> 2);
            n0 = P4[base4]; n1 = P4[base4 + 1]; n2 = P4[base4 + 2]; n3 = P4[base4 + 3];
            nprL = P[(size_t)(t + 1) * VCAB + lane];
            nprH = P[(size_t)(t + 1) * VCAB + 64 + lane];
        }

        // register gathers
        float ga = __shfl(prL, blank & 63, 64), gb = __shfl(prH, blank & 63, 64);
        const float prB = (blank < 64) ? ga : gb;
        float la_ = __shfl(prL, last_own & 63, 64), lb_ = __shfl(prH, last_own & 63, 64);
        const float prLast = (last_own < 64) ? la_ : lb_;

        // totals / act (one parallel lae)
        float ptot_own = lae(pb_own, pnb_own);
        unsigned long long bal = __ballot(ptot_own > ACTIVE_TH);
        unsigned actmask = (unsigned)bal & 0xFFu;
        bool act_own = (actmask >> own) & 1u;

        // own parent match by node-id identity (ids content-faithful via dedup)
        int p_own = 0;
        bool matched = false;
        {
            bool gate = act_own && (len_own > 0);
#pragma unroll
            for (int j = 0; j < 8; ++j) {
                bool m = gate && ((actmask >> j) & 1u) && (node8[j] == par_own);
                if (m) { p_own = j; matched = true; }
            }
        }
        float pbp = __shfl(pb_own, (lane & 56) | p_own, 64);
        float ptp = __shfl(ptot_own, (lane & 56) | p_own, 64);
        int lastp = 0;
#pragma unroll
        for (int j = 0; j < 8; ++j)
            if (p_own == j) lastp = (int)last8[j];
        float pprev = matched ? ((last_own == lastp) ? pbp : ptp) : LOG0f;

        // labels in my slice claimed as existing children of my beam
        unsigned claimed16 = 0;
#pragma unroll
        for (int j = 0; j < 8; ++j) {
            bool mj = ((actmask >> j) & 1u) && act_own && (node_own == par8[j]);
            bool ins = ((last8[j] >> 4) == (unsigned)slice);
            claimed16 |= (mj && ins) ? (1u << (last8[j] & 15u)) : 0u;
        }

        float contb_own = ptot_own + prB;
        float contnb_own = (len_own > 0) ? (lae(pnb_own, pprev) + prLast) : LOG0f;

        // candidate keys: 16 extensions (my beam x my slice) + cont on lanes 0..7
        // ref index space: [0..7]=continuations, [8..8+1024)=extensions i*V+v
        unsigned long long K[17];
#define MAKEK(c, pv)                                                                     \
        {                                                                                \
            int v = vbase + (c);                                                         \
            float prev = (v == last_own) ? pb_own : ptot_own;                            \
            float val = (pv) + prev;                                                     \
            bool bad = (v == blank) | ((pv) <= PRUNE_TH) | (!act_own) |                  \
                       (bool)((claimed16 >> (c)) & 1u);                                  \
            if (bad) val = LOG0f;                                                        \
            K[c] = (((unsigned long long)mono(val)) << 32) |                             \
                   (unsigned)~(8u + (unsigned)(own * VCAB + v));                         \
        }
        MAKEK(0, s0.x) MAKEK(1, s0.y) MAKEK(2, s0.z) MAKEK(3, s0.w)
        MAKEK(4, s1.x) MAKEK(5, s1.y) MAKEK(6, s1.z) MAKEK(7, s1.w)
        MAKEK(8, s2.x) MAKEK(9, s2.y) MAKEK(10, s2.z) MAKEK(11, s2.w)
        MAKEK(12, s3.x) MAKEK(13, s3.y) MAKEK(14, s3.z) MAKEK(15, s3.w)
#undef MAKEK
        {
            float tot = lae(contb_own, contnb_own);
            K[16] = (lane < 8)
                        ? ((((unsigned long long)mono(tot)) << 32) | (unsigned)~(unsigned)lane)
                        : 0ull;
        }

        // local sorted top-3 cache
        unsigned long long m1 = 0ull, m2 = 0ull, m3 = 0ull;
#pragma unroll
        for (int k = 0; k < 17; ++k) {
            unsigned long long key = K[k];
            bool g1 = key > m1, g2 = key > m2, g3 = key > m3;
            unsigned long long t1 = g1 ? key : m1;
            unsigned long long t2 = g1 ? m1 : (g2 ? key : m2);
            m3 = (g1 | g2) ? m2 : (g3 ? key : m3);
            m1 = t1; m2 = t2;
        }

        // top-8 extraction with strictly-decreasing bound W (keys globally unique)
        // ROLLED loop (code-size): per-round winner state staged via ls_a/ls_b (LDS)
        unsigned long long W = ~0ull;
        unsigned extmask = 0, insPar = 0, insRes = 0;
        int insLab = 0;
        float npb_own = LOG0f, npnb_own = LOG0f;
#pragma clang loop unroll(disable)
        for (int r = 0; r < 8; ++r) {
            unsigned long long c = (m1 < W) ? m1 : ((m2 < W) ? m2 : ((m3 < W) ? m3 : 0ull));
            bool exh = !(m3 < W);  // all 3 cache entries consumed -> need 4th
            if (__any(exh)) {
                if (exh) {
                    c = 0ull;
#pragma unroll
                    for (int k = 0; k < 17; ++k) {
                        bool g = (K[k] < W) && (K[k] > c);
                        c = g ? K[k] : c;
                    }
                }
            }
            unsigned ch = (unsigned)(c >> 32), cl = (unsigned)(c & 0xFFFFFFFFull);
            wave_max64(ch, cl);
            W = (((unsigned long long)ch) << 32) | cl;
            unsigned ssel = __builtin_amdgcn_readfirstlane(~cl);
            float val = mono_inv(ch);
            unsigned A, Bv;
            if (ssel < 8u) {  // continuation of beam ssel
                float cb = __shfl(contb_own, (lane & 56) | (int)ssel, 64);
                float cn = __shfl(contnb_own, (lane & 56) | (int)ssel, 64);
                if (own == r) { npb_own = cb; npnb_own = cn; }
                A = 0; Bv = 0;
#pragma unroll
                for (int j = 0; j < 8; ++j)
                    if (ssel == (unsigned)j) {
                        A = (node8[j] << 12) | par8[j];
                        Bv = (len8[j] << 7) | last8[j];
                    }
            } else {  // extension (src s, label lab); stored pnb == sort value bitwise
                unsigned e = ssel - 8u;
                unsigned s = e >> 7, lab = e & 127u;
                if (own == r) { npb_own = LOG0f; npnb_own = val; }
                unsigned nd = 0, ln = 0;
#pragma unroll
                for (unsigned j = 0; j < 8; ++j)
                    if (s == j) { nd = node8[j]; ln = len8[j]; }
                A = (0xFFFu << 12) | nd;  // node patched after hash; par = nd
                Bv = ((ln + 1u) << 7) | lab;
                extmask |= 1u << r;
                if (lane == r) { insPar = nd; insLab = (int)lab; }
            }
            if (lane == 0) { ls_a[r] = A; ls_b[r] = Bv; }
        }

        // dedup-hash inserts: lane r handles new beam r (deterministic pre-ids)
        if ((extmask >> lane) & 1u) {
            unsigned preid = 1u + 8u * (unsigned)t + (unsigned)lane;
            unsigned hkey = (insPar << 7) | (unsigned)insLab;
            unsigned entry = (hkey << 12) | preid;
            unsigned h = ((hkey * 2654435761u) >> 20) & HMASK;
            for (;;) {
                unsigned prev = atomicCAS(&hsh[h], HEMPTY, entry);
                if (prev == HEMPTY) { nodeinfo[preid] = hkey; insRes = preid; break; }
                if ((prev >> 12) == hkey) { insRes = prev & 0xFFFu; break; }
                h = (h + 1) & HMASK;
            }
        }
        // patch ext node ids + commit wave-uniform arrays (same-wave LDS readback)
#pragma unroll
        for (int j = 0; j < 8; ++j) {
            unsigned A = ls_a[j];
            unsigned Bv = ls_b[j];
            if ((extmask >> j) & 1u) {
                unsigned nd = __shfl(insRes, j, 64);
                A = (nd << 12) | (A & 0xFFFu);
            }
            A = __builtin_amdgcn_readfirstlane(A);
            Bv = __builtin_amdgcn_readfirstlane(Bv);
            node8[j] = A >> 12; par8[j] = A & 0xFFFu;
            len8[j] = Bv >> 7; last8[j] = Bv & 127u;
        }
        // own scalars from uniform arrays
        node_own = node8[0]; par_own = par8[0];
        len_own = (int)len8[0]; last_own = (int)last8[0];
#pragma unroll
        for (int j = 1; j < 8; ++j) {
            bool m = (own == j);
            node_own = m ? node8[j] : node_own;
            par_own = m ? par8[j] : par_own;
            len_own = m ? (int)len8[j] : len_own;
            last_own = m ? (int)last8[j] : last_own;
        }
        pb_own = npb_own; pnb_own = npnb_own;

        s0 = n0; s1 = n1; s2 = n2; s3 = n3;
        prL = nprL; prH = nprH;
    }

    // final argmax of totals (ties -> lowest index), then parent-walk reconstruction
    unsigned fh, fl;
    {
        float tot = lae(pb_own, pnb_own);
        fh = (lane < 8) ? mono(tot) : 0u;
        fl = (lane < 8) ? ~(unsigned)lane : 0u;
    }
    wave_max64(fh, fl);
    const int best = (int)(~fl);
    int L = 0;
    unsigned c = 0;
#pragma unroll
    for (int j = 0; j < 8; ++j)
        if (best == j) { L = (int)len8[j]; c = node8[j]; }
    if (lane == 0) {
        for (int k = L - 1; k >= 0; --k) {
            unsigned info = nodeinfo[c];
            sh_seq[k] = (int)(info & 127u);
            c = info >> 7;
        }
    }
    __syncthreads();
    for (int j = lane; j < T; j += 64)
        out_seq[(size_t)b * T + j] = (j < L) ? sh_seq[j] : 0;
    if (lane == 0) out_len[b] = L;
}

extern "C" void kernel_launch(void* const* d_in, const int* in_sizes, int n_in,
                              void* d_out, int out_size, void* d_ws, size_t ws_size,
                              hipStream_t stream) {
    const float* probs = (const float*)d_in[0];
    const int* lengths = (const int*)d_in[1];
    // d_in[2] = beam_width (fixed 8, compiled in); d_in[3] = blank_index
    const int* blank_p = (const int*)d_in[3];
    const int B = in_sizes[1];
    const int T = in_sizes[0] / (B * VCAB);
    int* out = (int*)d_out;
    ctc_beam_kernel<<<B, 64, 0, stream>>>(probs, lengths, blank_p, out,
                                          out + (size_t)B * T, T);
}

// Round 6
// 1336.563 us; speedup vs baseline: 1.2400x; 1.2400x over previous
//
#include <hip/hip_runtime.h>
#include <math.h>

#define LOG0f (-1.0e30f)
#define ACTIVE_TH (-1.0e29f)
#define PRUNE_TH (-9.0f)
#define VCAB 128
#define HSZ 4096
#define HMASK (HSZ - 1)
#define MAXN 2052
#define HEMPTY 0xFFFFFFFFu

// JAX-exact logaddexp: max + log1p(exp(-|a-b|)) in f32
__device__ __forceinline__ float lae(float a, float b) {
    float mx = fmaxf(a, b);
    float d = fabsf(a - b);
    return mx + log1pf(expf(-d));
}
// monotonic float->uint transform (order-preserving)
__device__ __forceinline__ unsigned mono(float f) {
    unsigned u = __float_as_uint(f);
    return (u & 0x80000000u) ? ~u : (u | 0x80000000u);
}
__device__ __forceinline__ float mono_inv(unsigned m) {
    unsigned u = (m & 0x80000000u) ? (m & 0x7FFFFFFFu) : ~m;
    return __uint_as_float(u);
}
__device__ __forceinline__ unsigned rlaneu(unsigned x, int l) {
    return (unsigned)__builtin_amdgcn_readlane((int)x, l);
}
__device__ __forceinline__ float rlanef(float x, int l) {
    return __uint_as_float(rlaneu(__float_as_uint(x), l));
}
// select a[s] from a statically-indexed 8-array (no scratch; works for uniform or varying s)
__device__ __forceinline__ unsigned sel8u(const unsigned a[8], unsigned s) {
    unsigned r = a[0];
#pragma unroll
    for (int j = 1; j < 8; ++j) r = (s == (unsigned)j) ? a[j] : r;
    return r;
}

// wave-wide max of u32: DPP up-sweep into lane 63 (rocPRIM gfx9 ladder), readlane -> uniform
__device__ __forceinline__ unsigned wred_max_u32(unsigned x) {
    unsigned y;
    y = (unsigned)__builtin_amdgcn_update_dpp(0, (int)x, 0x111, 0xf, 0xf, false);  // row_shr:1
    x = (y > x) ? y : x;
    y = (unsigned)__builtin_amdgcn_update_dpp(0, (int)x, 0x112, 0xf, 0xf, false);  // row_shr:2
    x = (y > x) ? y : x;
    y = (unsigned)__builtin_amdgcn_update_dpp(0, (int)x, 0x114, 0xf, 0xf, false);  // row_shr:4
    x = (y > x) ? y : x;
    y = (unsigned)__builtin_amdgcn_update_dpp(0, (int)x, 0x118, 0xf, 0xf, false);  // row_shr:8
    x = (y > x) ? y : x;
    y = (unsigned)__builtin_amdgcn_update_dpp(0, (int)x, 0x142, 0xa, 0xf, false);  // row_bcast:15
    x = (y > x) ? y : x;
    y = (unsigned)__builtin_amdgcn_update_dpp(0, (int)x, 0x143, 0xc, 0xf, false);  // row_bcast:31
    x = (y > x) ? y : x;
    return (unsigned)__builtin_amdgcn_readlane((int)x, 63);
}

__global__ __launch_bounds__(64)
void ctc_beam_kernel(const float* __restrict__ probs, const int* __restrict__ lengths,
                     const int* __restrict__ blank_p, int* __restrict__ out_seq,
                     int* __restrict__ out_len, int T) {
    __shared__ unsigned hsh[HSZ];        // dedup map (parent,label)->node: (hkey<<12)|id
    __shared__ unsigned nodeinfo[MAXN];  // (parent<<7)|label per node id
    __shared__ int sh_seq[256];

    const int lane = threadIdx.x;
    const int b = blockIdx.x;
    const int blank = blank_p[0];
    const int length = lengths[b];
    const float* __restrict__ P = probs + (size_t)b * T * VCAB;
    const float4* __restrict__ P4 = (const float4*)P;
    const int own = lane & 7;     // beam owned by this lane
    const int slice = lane >> 3;  // vocab slice [slice*16, +16)
    const int vbase = slice * 16;

    for (int i = lane; i < HSZ; i += 64) hsh[i] = HEMPTY;
    __syncthreads();

    // wave-uniform beam metadata
    unsigned node8[8], par8[8], len8[8], last8[8];
#pragma unroll
    for (int j = 0; j < 8; ++j) {
        node8[j] = 0; par8[j] = 0xFFFu; len8[j] = 0; last8[j] = (unsigned)blank;
    }
    // per-lane own-beam state (beam j's copy lives on every lane with own==j; lane j authoritative)
    float pb_own = (own == 0) ? 0.0f : LOG0f;  // root: blank prob = log(1)
    float pnb_own = LOG0f;
    int len_own = 0, last_own = blank;
    unsigned node_own = 0, par_own = 0xFFFu;

    // prefetch row 0: slice (float4 x4) + per-lane layout (labels lane, lane+64)
    float4 s0, s1, s2, s3;
    float prL, prH;
    {
        int base4 = (vbase >> 2);
        s0 = P4[base4]; s1 = P4[base4 + 1]; s2 = P4[base4 + 2]; s3 = P4[base4 + 3];
        prL = P[lane]; prH = P[64 + lane];
    }

#pragma clang loop unroll(disable)
    for (int t = 0; t < length; ++t) {
        // prefetch t+1
        float4 n0, n1, n2, n3;
        float nprL = 0.f, nprH = 0.f;
        n0 = n1 = n2 = n3 = make_float4(0.f, 0.f, 0.f, 0.f);
        if (t + 1 < length) {
            int base4 = (t + 1) * 32 + (vbase >> 2);
            n0 = P4[base4]; n1 = P4[base4 + 1]; n2 = P4[base4 + 2]; n3 = P4[base4 + 3];
            nprL = P[(size_t)(t + 1) * VCAB + lane];
            nprH = P[(size_t)(t + 1) * VCAB + 64 + lane];
        }

        float pt_own = lae(pb_own, pnb_own);
        unsigned long long bal = __ballot(pt_own > ACTIVE_TH);
        unsigned actmask = (unsigned)bal & 0xFFu;
        bool act_own = (actmask >> own) & 1u;

        // uniform per-beam tables via readlane (beam j authoritative on lane j)
        float pb8[8], pt8[8];
#pragma unroll
        for (int j = 0; j < 8; ++j) {
            pb8[j] = rlanef(pb_own, j);
            pt8[j] = rlanef(pt_own, j);
        }
        // uniform prob gathers via readlane (uniform indices)
        float prB = (blank < 64) ? rlanef(prL, blank) : rlanef(prH, blank - 64);
        float prv8[8];  // row prob at each beam's last label
#pragma unroll
        for (int j = 0; j < 8; ++j) {
            int lj = (int)last8[j];
            float a = rlanef(prL, lj & 63), c2 = rlanef(prH, lj & 63);
            prv8[j] = (lj < 64) ? a : c2;
        }

        // own parent match by node-id identity (ids content-faithful via dedup)
        int p_own = 0;
        bool matched = false;
        {
            bool gate = act_own && (len_own > 0);
#pragma unroll
            for (int j = 0; j < 8; ++j) {
                bool m = gate && ((actmask >> j) & 1u) && (node8[j] == par_own);
                if (m) { p_own = j; matched = true; }
            }
        }
        float pbp = pb8[0], ptp = pt8[0];
        int lastp = (int)last8[0];
#pragma unroll
        for (int j = 1; j < 8; ++j) {
            bool m = (p_own == j);
            pbp = m ? pb8[j] : pbp;
            ptp = m ? pt8[j] : ptp;
            lastp = m ? (int)last8[j] : lastp;
        }
        float pprev = matched ? ((last_own == lastp) ? pbp : ptp) : LOG0f;
        float prLast = prv8[0];
#pragma unroll
        for (int j = 1; j < 8; ++j) prLast = (own == j) ? prv8[j] : prLast;

        float contb_own = pt_own + prB;
        float contnb_own = (len_own > 0) ? (lae(pnb_own, pprev) + prLast) : LOG0f;
        float tot_own = lae(contb_own, contnb_own);

        // labels in my slice claimed as existing children of my beam
        unsigned claimed16 = 0;
#pragma unroll
        for (int j = 0; j < 8; ++j) {
            bool mj = ((actmask >> j) & 1u) && act_own && (node_own == par8[j]);
            bool ins = ((last8[j] >> 4) == (unsigned)slice);
            claimed16 |= (mj && ins) ? (1u << (last8[j] & 15u)) : 0u;
        }

        // candidate keys: 16 extensions (my beam x my slice) + cont on lanes 0..7
        // ref index space: [0..7]=continuations, [8..8+1024)=extensions i*V+v
        unsigned long long K[17];
#define MAKEK(c, pv)                                                                     \
        {                                                                                \
            int v = vbase + (c);                                                         \
            float prev = (v == last_own) ? pb_own : pt_own;                              \
            float val = (pv) + prev;                                                     \
            bool bad = (v == blank) | ((pv) <= PRUNE_TH) | (!act_own) |                  \
                       (bool)((claimed16 >> (c)) & 1u);                                  \
            if (bad) val = LOG0f;                                                        \
            K[c] = (((unsigned long long)mono(val)) << 32) |                             \
                   (unsigned)~(8u + (unsigned)(own * VCAB + v));                         \
        }
        MAKEK(0, s0.x) MAKEK(1, s0.y) MAKEK(2, s0.z) MAKEK(3, s0.w)
        MAKEK(4, s1.x) MAKEK(5, s1.y) MAKEK(6, s1.z) MAKEK(7, s1.w)
        MAKEK(8, s2.x) MAKEK(9, s2.y) MAKEK(10, s2.z) MAKEK(11, s2.w)
        MAKEK(12, s3.x) MAKEK(13, s3.y) MAKEK(14, s3.z) MAKEK(15, s3.w)
#undef MAKEK
        K[16] = (lane < 8)
                    ? ((((unsigned long long)mono(tot_own)) << 32) | (unsigned)~(unsigned)lane)
                    : 0ull;

        // local sorted top-3 cache
        unsigned long long m1 = 0ull, m2 = 0ull, m3 = 0ull;
#pragma unroll
        for (int k = 0; k < 17; ++k) {
            unsigned long long key = K[k];
            bool g1 = key > m1, g2 = key > m2, g3 = key > m3;
            unsigned long long t1 = g1 ? key : m1;
            unsigned long long t2 = g1 ? m1 : (g2 ? key : m2);
            m3 = (g1 | g2) ? m2 : (g3 ? key : m3);
            m1 = t1; m2 = t2;
        }

        // top-8 extraction: strictly-decreasing bound W, two-phase 32-bit wave argmax
        unsigned long long W = ~0ull;
        unsigned selh[8], sell[8];
        bool dead = false;
#pragma unroll
        for (int r = 0; r < 8; ++r) {
            unsigned long long c = (m1 < W) ? m1 : ((m2 < W) ? m2 : ((m3 < W) ? m3 : 0ull));
            bool need = (c == 0ull) && !dead;  // cache consumed -> tree rescan (rare)
            if (__any(need)) {
                if (need) {
                    unsigned long long tt[17];
#pragma unroll
                    for (int k = 0; k < 17; ++k) tt[k] = (K[k] < W) ? K[k] : 0ull;
#pragma unroll
                    for (int s = 1; s < 17; s <<= 1) {
#pragma unroll
                        for (int k = 0; k + s < 17; k += 2 * s)
                            tt[k] = (tt[k] > tt[k + s]) ? tt[k] : tt[k + s];
                    }
                    c = tt[0];
                    if (c == 0ull) {
                        dead = true;  // no keys below W remain on this lane
                    } else {
                        m1 = c; m2 = ~0ull; m3 = ~0ull;  // poison: rescan when m1 consumed
                    }
                }
            }
            unsigned ch = (unsigned)(c >> 32), cl = (unsigned)c;
            unsigned M = wred_max_u32(ch);            // winner value word (uniform)
            unsigned lo2 = (ch == M) ? cl : 0u;
            unsigned L = wred_max_u32(lo2);           // winner ~refidx (max = lowest idx)
            W = (((unsigned long long)M) << 32) | L;
            selh[r] = M; sell[r] = L;
        }

        // decode winners (all uniform scalars)
        float npb_own = LOG0f, npnb_own = LOG0f;
        unsigned nn8[8], np8[8], nl8[8], nla8[8];
        unsigned extmask = 0, insPar = 0, insRes = 0;
        int insLab = 0;
#pragma unroll
        for (int r = 0; r < 8; ++r) {
            unsigned sel = ~sell[r];
            if (sel < 8u) {  // continuation of beam sel
                int s = (int)sel;
                float cb = rlanef(contb_own, s);
                float cn = rlanef(contnb_own, s);
                if (own == r) { npb_own = cb; npnb_own = cn; }
                nn8[r] = sel8u(node8, sel);
                np8[r] = sel8u(par8, sel);
                nl8[r] = sel8u(len8, sel);
                nla8[r] = sel8u(last8, sel);
            } else {  // extension (src s, label lab); stored pnb == sort value bitwise
                unsigned e = sel - 8u;
                unsigned s = e >> 7, lab = e & 127u;
                float val = mono_inv(selh[r]);
                if (own == r) { npb_own = LOG0f; npnb_own = val; }
                unsigned nd = sel8u(node8, s), ln = sel8u(len8, s);
                nn8[r] = 0u; np8[r] = nd; nl8[r] = ln + 1u; nla8[r] = lab;
                extmask |= 1u << r;
                if ((unsigned)lane == (unsigned)r) { insPar = nd; insLab = (int)lab; }
            }
        }

        // dedup-hash inserts: lane r handles new beam r (deterministic pre-ids)
        if ((extmask >> lane) & 1u) {
            unsigned preid = 1u + 8u * (unsigned)t + (unsigned)lane;
            unsigned hkey = (insPar << 7) | (unsigned)insLab;
            unsigned entry = (hkey << 12) | preid;
            unsigned h = ((hkey * 2654435761u) >> 20) & HMASK;
            for (;;) {
                unsigned prev = atomicCAS(&hsh[h], HEMPTY, entry);
                if (prev == HEMPTY) { nodeinfo[preid] = hkey; insRes = preid; break; }
                if ((prev >> 12) == hkey) { insRes = prev & 0xFFFu; break; }
                h = (h + 1) & HMASK;
            }
        }
        // patch ext node ids via readlane from the inserting lane + commit
#pragma unroll
        for (int r = 0; r < 8; ++r) {
            unsigned nd = nn8[r];
            if ((extmask >> r) & 1u) nd = rlaneu(insRes, r);  // uniform condition
            node8[r] = nd; par8[r] = np8[r]; len8[r] = nl8[r]; last8[r] = nla8[r];
        }
        node_own = sel8u(node8, (unsigned)own);
        par_own = sel8u(par8, (unsigned)own);
        len_own = (int)sel8u(len8, (unsigned)own);
        last_own = (int)sel8u(last8, (unsigned)own);
        pb_own = npb_own; pnb_own = npnb_own;

        s0 = n0; s1 = n1; s2 = n2; s3 = n3;
        prL = nprL; prH = nprH;
    }

    // final argmax of totals (ties -> lowest index), then parent-walk reconstruction
    unsigned fh, fl;
    {
        float tot = lae(pb_own, pnb_own);
        fh = (lane < 8) ? mono(tot) : 0u;
        fl = (lane < 8) ? ~(unsigned)lane : 0u;
    }
    {
        unsigned M = wred_max_u32(fh);
        unsigned lo2 = (fh == M) ? fl : 0u;
        fl = wred_max_u32(lo2);
    }
    const int best = (int)(~fl);
    int L = 0;
    unsigned c = 0;
#pragma unroll
    for (int j = 0; j < 8; ++j)
        if (best == j) { L = (int)len8[j]; c = node8[j]; }
    if (lane == 0) {
        for (int k = L - 1; k >= 0; --k) {
            unsigned info = nodeinfo[c];
            sh_seq[k] = (int)(info & 127u);
            c = info >> 7;
        }
    }
    __syncthreads();
    for (int j = lane; j < T; j += 64)
        out_seq[(size_t)b * T + j] = (j < L) ? sh_seq[j] : 0;
    if (lane == 0) out_len[b] = L;
}

extern "C" void kernel_launch(void* const* d_in, const int* in_sizes, int n_in,
                              void* d_out, int out_size, void* d_ws, size_t ws_size,
                              hipStream_t stream) {
    const float* probs = (const float*)d_in[0];
    const int* lengths = (const int*)d_in[1];
    // d_in[2] = beam_width (fixed 8, compiled in); d_in[3] = blank_index
    const int* blank_p = (const int*)d_in[3];
    const int B = in_sizes[1];
    const int T = in_sizes[0] / (B * VCAB);
    int* out = (int*)d_out;
    ctc_beam_kernel<<<B, 64, 0, stream>>>(probs, lengths, blank_p, out,
                                          out + (size_t)B * T, T);
}